// Round 8
// baseline (215.909 us; speedup 1.0000x reference)
//
#include <hip/hip_runtime.h>
#include <hip/hip_bf16.h>

// AKConv fp32 in/out, bf16 MFMA everywhere.
//  k_prep  : fused {BN fold + A-frag pre-swizzles} U {x -> xT/xTlo channel-last}
//  k_offset: 3x3 offset conv as double-bf16 MFMA GEMM + bilinear tables
//  k_main  : fused gather + MFMA GEMM (M=256,K=640,N=51200) + BN + SiLU.
//            BARRIER-FREE: 1 wave = 32 px x full M=256 (16 mt x 2 nt, acc=128).
//            B-frags gathered directly into registers (no LDS staging).

typedef __attribute__((ext_vector_type(8))) short short8;
typedef __attribute__((ext_vector_type(4))) float f32x4;

#define Bsz 8
#define C1 128
#define C2 256
#define HW 6400
#define NP 5

// ---- workspace layout (bytes) ----
#define NPOS (Bsz*NP*HW)                    // 256000 samples
#define WS_IDX4 0                           // int4[NPOS]: corner BYTE offsets into xT image
#define WS_WGT4 (WS_IDX4 + NPOS*16)         // float4[NPOS]
#define WS_XT   (WS_WGT4 + NPOS*16)         // ushort xT[8][6400][128]   13.1 MB (hi)
#define WS_XTLO (WS_XT + Bsz*HW*C1*2)       // ushort xTlo[8][6400][128] 13.1 MB (residual)
#define WS_ACW  (WS_XTLO + Bsz*HW*C1*2)     // ushort acw[163840]  (cw A-frags)
#define WS_APWH (WS_ACW + C2*C1*NP*2)       // ushort apw_hi[18432]
#define WS_APWL (WS_APWH + 18432*2)         // ushort apw_lo[18432]
#define WS_BNS  (WS_APWL + 18432*2)
#define WS_BNT  (WS_BNS + 1024)

__device__ __forceinline__ unsigned short f2bf(float f) {
  __hip_bfloat16 h = __float2bfloat16(f);
  return reinterpret_cast<unsigned short&>(h);
}
__device__ __forceinline__ float bfu2f(unsigned short u) {
  unsigned int v = ((unsigned int)u) << 16;
  return reinterpret_cast<float&>(v);
}

// ---- K0: fused pre-swizzle (blocks 0..711) + transpose (blocks 712..2311) ---
__global__ __launch_bounds__(256) void k_prep(
    const float* __restrict__ x, const float* __restrict__ cw,
    const float* __restrict__ pw,
    const float* __restrict__ gam, const float* __restrict__ bet,
    const float* __restrict__ mu, const float* __restrict__ var,
    unsigned short* __restrict__ xT, unsigned short* __restrict__ xTlo,
    unsigned short* __restrict__ acw, unsigned short* __restrict__ apwh,
    unsigned short* __restrict__ apwl,
    float* __restrict__ bns, float* __restrict__ bnt) {
  __shared__ float lds[128][33];
  int t = threadIdx.x;
  if (blockIdx.x < 712) {
    int i = blockIdx.x * 256 + t;                  // 182272 = 163840+18432
    if (i < 163840) {
      int j = i & 7, lane = (i >> 3) & 63, mtile = (i >> 9) & 15;
      int cc = (i >> 13) & 3, k = i >> 15;
      int m = mtile * 16 + (lane & 15);
      int c = cc * 32 + (lane >> 4) * 8 + j;
      acw[i] = f2bf(cw[(m * C1 + c) * NP + k]);
    } else {
      int i2 = i - 163840;                         // 18432 elements
      int j = i2 & 7, lane = (i2 >> 3) & 63, chunk = i2 >> 9;
      int m = lane & 15, tap = chunk >> 2;
      int c = (chunk & 3) * 32 + (lane >> 4) * 8 + j;
      float wv = (m < 10) ? pw[(m * C1 + c) * 9 + tap] : 0.f;
      unsigned short hi = f2bf(wv);
      apwh[i2] = hi;
      apwl[i2] = f2bf(wv - bfu2f(hi));
    }
    if (blockIdx.x == 0) {
      float s = gam[t] * rsqrtf(var[t] + 1e-5f);
      bns[t] = s;
      bnt[t] = bet[t] - mu[t] * s;
    }
    return;
  }
  // ---- transpose part: 1600 blocks of 32 pixels
  int gp0 = (blockIdx.x - 712) * 32;
  int b = gp0 / HW, p0 = gp0 - b * HW;
  const float* xb = x + (size_t)b * C1 * HW;
  int q = t & 7, r = t >> 3;                       // q: px-quad, r: channel 0..31
#pragma unroll
  for (int pass = 0; pass < 4; ++pass) {
    int c = pass * 32 + r;
    float4 v = *(const float4*)(xb + (size_t)c * HW + p0 + q * 4);
    lds[c][q * 4 + 0] = v.x;
    lds[c][q * 4 + 1] = v.y;
    lds[c][q * 4 + 2] = v.z;
    lds[c][q * 4 + 3] = v.w;
  }
  __syncthreads();
  int px = t >> 3, u = t & 7;                      // px 0..31, unit 0..7
#pragma unroll
  for (int it = 0; it < 2; ++it) {
    int unit = it * 8 + u;
    int c0 = unit * 8;
    unsigned short vh[8], vl[8];
#pragma unroll
    for (int e = 0; e < 8; ++e) {
      float f = lds[c0 + e][px];
      unsigned short h = f2bf(f);
      vh[e] = h;
      vl[e] = f2bf(f - bfu2f(h));
    }
    size_t base = (size_t)(gp0 + px) * C1 + unit * 8;
    *(uint4*)(xT + base) = *(uint4*)vh;
    *(uint4*)(xTlo + base) = *(uint4*)vl;
  }
}

// ---- K1: offset conv via double-bf16 MFMA + bilinear tables ----------------
// One wave per block, 16 pixels per wave, grid 3200.
__global__ __launch_bounds__(64) void k_offset(
    const unsigned short* __restrict__ xT, const unsigned short* __restrict__ xTlo,
    const unsigned short* __restrict__ apwh, const unsigned short* __restrict__ apwl,
    const float* __restrict__ pb,
    int4* __restrict__ idx4, float4* __restrict__ wgt4) {
  __shared__ float sOff[10][16];
  int t = threadIdx.x, lane = t;
  int n16 = lane & 15, koct = lane >> 4;
  int gp = blockIdx.x * 16 + n16;
  int b = gp / HW, p = gp - b * HW;
  int h = p / 80, w = p - h * 80;
  const char* xTb = (const char*)xT + (size_t)b * HW * 256;
  const char* xTlb = (const char*)xTlo + (size_t)b * HW * 256;

  f32x4 acc = (f32x4)(0.f);
#pragma unroll
  for (int chunk = 0; chunk < 36; ++chunk) {
    int tap = chunk >> 2, cc = chunk & 3;
    int dh = tap / 3 - 1, dw = tap - (tap / 3) * 3 - 1;
    int hh = h + dh, ww = w + dw;
    bool ok = ((unsigned)hh < 80u) && ((unsigned)ww < 80u);
    short8 bh = 0, bl = 0;
    if (ok) {
      int boff = ((hh * 80 + ww) << 8) + cc * 64 + koct * 16;
      bh = *(const short8*)(xTb + boff);
      bl = *(const short8*)(xTlb + boff);
    }
    short8 ah = *(const short8*)(apwh + (chunk * 64 + lane) * 8);
    short8 al = *(const short8*)(apwl + (chunk * 64 + lane) * 8);
    acc = __builtin_amdgcn_mfma_f32_16x16x32_bf16(ah, bh, acc, 0, 0, 0);
    acc = __builtin_amdgcn_mfma_f32_16x16x32_bf16(ah, bl, acc, 0, 0, 0);
    acc = __builtin_amdgcn_mfma_f32_16x16x32_bf16(al, bh, acc, 0, 0, 0);
  }

  int quad = lane >> 4;
#pragma unroll
  for (int r = 0; r < 4; ++r) {
    int row = quad * 4 + r;
    if (row < 10) sOff[row][n16] = acc[r];
  }
  __syncthreads();

  for (int task = t; task < 80; task += 64) {
    int k = task >> 4, n = task & 15;
    int gp2 = blockIdx.x * 16 + n;
    int b2 = gp2 / HW, p2 = gp2 - b2 * HW;
    int h2 = p2 / 80, w2 = p2 - h2 * 80;
    float px = sOff[k][n] + pb[k] + (float)(h2 + (k >> 1));
    float py = sOff[5 + k][n] + pb[5 + k] + (float)(w2 + (k & 1));
    float pf = floorf(px), qf = floorf(py);
    float x0 = fminf(fmaxf(pf, 0.f), 79.f);
    float x1 = fminf(fmaxf(pf + 1.f, 0.f), 79.f);
    float y0 = fminf(fmaxf(qf, 0.f), 79.f);
    float y1 = fminf(fmaxf(qf + 1.f, 0.f), 79.f);
    float pxc = fminf(fmaxf(px, 0.f), 79.f);
    float pyc = fminf(fmaxf(py, 0.f), 79.f);
    float wx0 = 1.f + (x0 - pxc), wx1 = 1.f - (x1 - pxc);
    float wy0 = 1.f + (y0 - pyc), wy1 = 1.f - (y1 - pyc);
    int ix0 = (int)x0, ix1 = (int)x1, iy0 = (int)y0, iy1 = (int)y1;
    int g = (b2 * NP + k) * HW + p2;
    idx4[g] = make_int4((ix0 * 80 + iy0) << 8, (ix1 * 80 + iy1) << 8,
                        (ix0 * 80 + iy1) << 8, (ix1 * 80 + iy0) << 8);
    wgt4[g] = make_float4(wx0 * wy0, wx1 * wy1, wx0 * wy1, wx1 * wy0);
  }
}

// ---- K3: barrier-free fused gather + MFMA GEMM + BN + SiLU -----------------
// 1600 single-wave blocks. Wave: 32 px (2 nt) x all 256 m (16 mt).
// Per 32-K chunk: 8 gather loads (16 lines each, 4 lanes/64B line), 16 A-frag
// loads from L2-hot acw, 32 MFMA. No LDS, no __syncthreads.
__global__ __launch_bounds__(64) void k_main(
    const unsigned short* __restrict__ xT,
    const unsigned short* __restrict__ acw,
    const int4* __restrict__ idx4, const float4* __restrict__ wgt4,
    const float* __restrict__ bns, const float* __restrict__ bnt,
    float* __restrict__ out) {
  int lane = threadIdx.x;
  int gp0 = blockIdx.x * 32;
  int b = gp0 / HW, pbase = gp0 - b * HW;
  int n16 = lane & 15, koct = lane >> 4;
  const char* xTb = (const char*)xT + (size_t)b * HW * 256;
  size_t sampBase = (size_t)b * NP * HW + pbase;

  f32x4 acc[16][2];
#pragma unroll
  for (int mt = 0; mt < 16; ++mt) {
    acc[mt][0] = (f32x4)(0.f);
    acc[mt][1] = (f32x4)(0.f);
  }

#pragma unroll
  for (int k = 0; k < NP; ++k) {
    int4 id[2];
    float4 wg[2];
#pragma unroll
    for (int nt = 0; nt < 2; ++nt) {
      size_t g = sampBase + (size_t)k * HW + nt * 16 + n16;
      id[nt] = idx4[g];
      wg[nt] = wgt4[g];
    }
#pragma unroll
    for (int cc = 0; cc < 4; ++cc) {
      int cb = cc * 64 + koct * 16;
      short8 bfr[2];
#pragma unroll
      for (int nt = 0; nt < 2; ++nt) {
        union { uint4 v; unsigned short u[8]; } q0, q1, q2, q3, rr;
        q0.v = *(const uint4*)(xTb + id[nt].x + cb);
        q1.v = *(const uint4*)(xTb + id[nt].y + cb);
        q2.v = *(const uint4*)(xTb + id[nt].z + cb);
        q3.v = *(const uint4*)(xTb + id[nt].w + cb);
#pragma unroll
        for (int e = 0; e < 8; ++e) {
          float f = wg[nt].x * bfu2f(q0.u[e]) + wg[nt].y * bfu2f(q1.u[e])
                  + wg[nt].z * bfu2f(q2.u[e]) + wg[nt].w * bfu2f(q3.u[e]);
          rr.u[e] = f2bf(f);
        }
        bfr[nt] = *(short8*)&rr;
      }
      const unsigned short* ab =
          acw + ((size_t)((k * 4 + cc) * 16) * 64 + lane) * 8;
#pragma unroll
      for (int mt = 0; mt < 16; ++mt) {
        short8 a = *(const short8*)(ab + (size_t)mt * 64 * 8);
        acc[mt][0] = __builtin_amdgcn_mfma_f32_16x16x32_bf16(
            a, bfr[0], acc[mt][0], 0, 0, 0);
        acc[mt][1] = __builtin_amdgcn_mfma_f32_16x16x32_bf16(
            a, bfr[1], acc[mt][1], 0, 0, 0);
      }
    }
  }

  // ---- epilogue: BN + SiLU
  int quad = lane >> 4, col = lane & 15;
#pragma unroll
  for (int mt = 0; mt < 16; ++mt) {
#pragma unroll
    for (int r = 0; r < 4; ++r) {
      int m = mt * 16 + quad * 4 + r;
      float s = bns[m], sh = bnt[m];
      float* op = out + ((size_t)(b * C2 + m)) * HW + pbase;
#pragma unroll
      for (int nt = 0; nt < 2; ++nt) {
        float y = fmaf(acc[mt][nt][r], s, sh);
        op[nt * 16 + col] = y * (1.f / (1.f + __expf(-y)));
      }
    }
  }
}

extern "C" void kernel_launch(void* const* d_in, const int* in_sizes, int n_in,
                              void* d_out, int out_size, void* d_ws, size_t ws_size,
                              hipStream_t stream) {
  const float* x  = (const float*)d_in[0];
  const float* pw = (const float*)d_in[1];
  const float* pb = (const float*)d_in[2];
  const float* cw = (const float*)d_in[3];
  const float* bg = (const float*)d_in[4];
  const float* bb = (const float*)d_in[5];
  const float* bm = (const float*)d_in[6];
  const float* bv = (const float*)d_in[7];
  float* out = (float*)d_out;

  char* ws = (char*)d_ws;
  int4*           idx4 = (int4*)(ws + WS_IDX4);
  float4*         wgt4 = (float4*)(ws + WS_WGT4);
  unsigned short* xT   = (unsigned short*)(ws + WS_XT);
  unsigned short* xTlo = (unsigned short*)(ws + WS_XTLO);
  unsigned short* acw  = (unsigned short*)(ws + WS_ACW);
  unsigned short* apwh = (unsigned short*)(ws + WS_APWH);
  unsigned short* apwl = (unsigned short*)(ws + WS_APWL);
  float*          bns  = (float*)(ws + WS_BNS);
  float*          bnt  = (float*)(ws + WS_BNT);

  k_prep<<<2312, 256, 0, stream>>>(x, cw, pw, bg, bb, bm, bv,
                                   xT, xTlo, acw, apwh, apwl, bns, bnt);
  k_offset<<<3200, 64, 0, stream>>>(xT, xTlo, apwh, apwl, pb, idx4, wgt4);
  k_main<<<1600, 64, 0, stream>>>(xT, acw, idx4, wgt4, bns, bnt, out);
}